// Round 6
// baseline (359.752 us; speedup 1.0000x reference)
//
#include <hip/hip_runtime.h>
#include <math.h>
#include <limits.h>

#define BB 8
#define SS 4096
#define HH 1024
#define EE 256
#define KK 64
#define HQ 256
#define NEGF -1e30f

typedef short bf16x8 __attribute__((ext_vector_type(8)));
typedef float f32x4  __attribute__((ext_vector_type(4)));

__device__ inline short f2bf(float x) {
    unsigned u = __float_as_uint(x);
    unsigned r = (u + 0x7fffu + ((u >> 16) & 1u)) >> 16;   // RNE
    return (short)r;
}

// pack two f32 into two bf16 (round-half-up)
__device__ inline unsigned pk2bf(float lo, float hi) {
    unsigned a = __float_as_uint(lo) + 0x8000u;
    unsigned b = __float_as_uint(hi) + 0x8000u;
    return (a >> 16) | (b & 0xffff0000u);
}

// Both weight conversions in one kernel. dst[kb][n][kk] = bf16(src[(kb*32+kk)*HQ+n])
__global__ __launch_bounds__(256) void convert_both_kernel(
    const float* __restrict__ tok_w1, const float* __restrict__ blk_w1,
    short* __restrict__ w1s_tok, short* __restrict__ w1s_blk)
{
    const int kb = blockIdx.x & 31, which = blockIdx.x >> 5;
    const float* src = which ? blk_w1 : tok_w1;
    short* dst = which ? w1s_blk : w1s_tok;
    const int n = threadIdx.x;
    for (int kk = 0; kk < 32; kk++)
        dst[kb * 8192 + n * 32 + kk] = f2bf(src[(kb * 32 + kk) * HQ + n]);
}

// Row scores: 32 rows/WG x 256 cols. Linear X fetch (WG's 32 rows = one
// contiguous 128 KB block, whole rows per load instruction), whole-K tile in
// LDS (64 KB, fragment-ordered conflict-free reads), B via 4-deep register
// ring. NORMAL (cached) X loads: the following block_embed kernel re-reads
// the same 134 MB, and L3 retains ~half of it (r5's nontemporal variant cost
// +20us pipeline by killing that reuse). Zero barriers in the main loop.
__global__ __launch_bounds__(256, 2) void mfma_score32L_kernel(
    const float* __restrict__ X, const short* __restrict__ w1s,
    const float* __restrict__ b1, const float* __restrict__ w2,
    const float* __restrict__ b2, float* __restrict__ out)
{
    __shared__ __attribute__((aligned(16))) short As[32][1024];  // 64 KB
    __shared__ float part[4][32];
    short* const AsF = &As[0][0];

    const int t = threadIdx.x;
    const int wv = t >> 6, lane = t & 63, lo = lane & 15, q = lane >> 4;
    const long row0 = (long)blockIdx.x * 32;

    f32x4 acc[2][4];
#pragma unroll
    for (int i = 0; i < 2; i++)
#pragma unroll
        for (int j = 0; j < 4; j++) acc[i][j] = (f32x4){0.f, 0.f, 0.f, 0.f};

    // B: wave wv, frag ct: lane(q,lo) -> n = wv*64+ct*16+lo, k = kb*32+q*8
    const short* wp = w1s + (wv * 64 + lo) * 32 + q * 8;
    bf16x8 bR[4][4];     // 4-deep k-step prefetch ring
#pragma unroll
    for (int kk = 0; kk < 4; kk++)
#pragma unroll
        for (int ct = 0; ct < 4; ct++)
            bR[kk][ct] = *(const bf16x8*)(wp + kk * 8192 + ct * 512);

    // ---- linear staging: thread t owns cols 4t..4t+3 of every row ----
    // element (row, k): kstep kb=k>>5, q2=(k>>3)&3, e=k&7. For k=4t+c:
    // kb=t>>3, q2=(t>>1)&3, e=(t&1)*4+c  ->  short idx =
    // (t>>3)*1024 + ((row>>4)*64 + q2*16 + (row&15))*8 + (t&1)*4 + c
    const int tconst = ((t >> 3) << 10) + (((t >> 1) & 3) << 7) + ((t & 1) << 2);
    const float* xt = X + row0 * HH + 4 * t;

    f32x4 va[8], vb[8];
#pragma unroll
    for (int j = 0; j < 8; j++)
        va[j] = *(const f32x4*)(xt + j * HH);
#pragma unroll
    for (int j = 0; j < 8; j++)
        vb[j] = *(const f32x4*)(xt + (8 + j) * HH);

#define STASH(ROW, V)                                                          \
    {                                                                          \
        const int idx_ = tconst + (((ROW) >> 4) << 9) + (((ROW) & 15) << 3);   \
        uint2 u_; u_.x = pk2bf((V).x, (V).y); u_.y = pk2bf((V).z, (V).w);      \
        *(uint2*)&AsF[idx_] = u_;                                              \
    }

#pragma unroll
    for (int j = 0; j < 8; j++) STASH(j, va[j])
#pragma unroll
    for (int j = 0; j < 8; j++)
        va[j] = *(const f32x4*)(xt + (16 + j) * HH);
#pragma unroll
    for (int j = 0; j < 8; j++) STASH(8 + j, vb[j])
#pragma unroll
    for (int j = 0; j < 8; j++)
        vb[j] = *(const f32x4*)(xt + (24 + j) * HH);
#pragma unroll
    for (int j = 0; j < 8; j++) STASH(16 + j, va[j])
#pragma unroll
    for (int j = 0; j < 8; j++) STASH(24 + j, vb[j])
#undef STASH
    __syncthreads();

    // ---- main loop: no barriers; As read-only, B ring in registers ----
    for (int cb = 0; cb < 8; cb++) {
#pragma unroll
        for (int jj = 0; jj < 4; jj++) {
            const int kb = cb * 4 + jj;
            const bf16x8 af0 = *(const bf16x8*)&AsF[(kb << 10) + ((q * 16 + lo) << 3)];
            const bf16x8 af1 = *(const bf16x8*)&AsF[(kb << 10) + ((64 + q * 16 + lo) << 3)];
#pragma unroll
            for (int ct = 0; ct < 4; ct++) {
                acc[0][ct] = __builtin_amdgcn_mfma_f32_16x16x32_bf16(
                    af0, bR[jj][ct], acc[0][ct], 0, 0, 0);
                acc[1][ct] = __builtin_amdgcn_mfma_f32_16x16x32_bf16(
                    af1, bR[jj][ct], acc[1][ct], 0, 0, 0);
            }
            const int kn = (kb + 4 < 32) ? kb + 4 : 31;   // dummy clamp at tail
#pragma unroll
            for (int ct = 0; ct < 4; ct++)
                bR[jj][ct] = *(const bf16x8*)(wp + kn * 8192 + ct * 512);
        }
    }

    // epilogue: rowpart[rt][r] = sum_c tanh(acc + b1[c]) * w2[c]
    float rowpart[2][4];
#pragma unroll
    for (int rt = 0; rt < 2; rt++)
#pragma unroll
        for (int r = 0; r < 4; r++) rowpart[rt][r] = 0.f;
#pragma unroll
    for (int ct = 0; ct < 4; ct++) {
        const int cc = wv * 64 + ct * 16 + lo;
        const float b1c = b1[cc], w2c = w2[cc];
#pragma unroll
        for (int rt = 0; rt < 2; rt++)
#pragma unroll
            for (int r = 0; r < 4; r++)
                rowpart[rt][r] += tanhf(acc[rt][ct][r] + b1c) * w2c;
    }
#pragma unroll
    for (int rt = 0; rt < 2; rt++)
#pragma unroll
        for (int r = 0; r < 4; r++) {
            float v = rowpart[rt][r];
            v += __shfl_down(v, 8, 64);
            v += __shfl_down(v, 4, 64);
            v += __shfl_down(v, 2, 64);
            v += __shfl_down(v, 1, 64);
            rowpart[rt][r] = v;   // valid where lo==0
        }
    if (lo == 0)
#pragma unroll
        for (int rt = 0; rt < 2; rt++)
#pragma unroll
            for (int r = 0; r < 4; r++)
                part[wv][rt * 16 + q * 4 + r] = rowpart[rt][r];
    __syncthreads();
    if (t < 32)
        out[row0 + t] = part[0][t] + part[1][t] + part[2][t] + part[3][t] + b2[0];
}

// Per (b,k): masked max + denom; write normalized wtok; zero embed row;
// k==0 also zeroes wtok[0, start).
__global__ __launch_bounds__(256) void block_stats_kernel(
    const float* __restrict__ scores, const int* __restrict__ mask,
    const int* __restrict__ bnd, float* __restrict__ bden,
    float* __restrict__ wtok, float* __restrict__ embed)
{
    const int b = blockIdx.x >> 6, k = blockIdx.x & 63;
    const int start = bnd[b * KK + k];
    const int end = (k == KK - 1) ? SS : bnd[b * KK + k + 1];
    const int tid = threadIdx.x;
    __shared__ float r[4];
    __shared__ float mshared, dshared;

    // zero this block's embed row (embed kernel runs after us)
    *((float4*)(embed + (long)blockIdx.x * HH) + tid) = (float4){0.f, 0.f, 0.f, 0.f};
    // zero the uncovered wtok prefix
    if (k == 0)
        for (int s = tid; s < start; s += 256) wtok[b * SS + s] = 0.f;

    float m = NEGF;
    for (int s = start + tid; s < end; s += 256)
        if (mask[b * SS + s] == 1) m = fmaxf(m, scores[b * SS + s]);
    for (int off = 32; off > 0; off >>= 1) m = fmaxf(m, __shfl_down(m, off, 64));
    if ((tid & 63) == 0) r[tid >> 6] = m;
    __syncthreads();
    if (tid == 0) mshared = fmaxf(fmaxf(r[0], r[1]), fmaxf(r[2], r[3]));
    __syncthreads();
    m = mshared;

    float d = 0.f;
    for (int s = start + tid; s < end; s += 256)
        if (mask[b * SS + s] == 1) d += expf(scores[b * SS + s] - m);
    for (int off = 32; off > 0; off >>= 1) d += __shfl_down(d, off, 64);
    __syncthreads();
    if ((tid & 63) == 0) r[tid >> 6] = d;
    __syncthreads();
    if (tid == 0) {
        float den = r[0] + r[1] + r[2] + r[3];
        bden[blockIdx.x] = den;
        dshared = (den > 0.f) ? 1.f / fmaxf(den, 1e-30f) : 0.f;
    }
    __syncthreads();
    const float inv = dshared;
    for (int s = start + tid; s < end; s += 256)
        wtok[b * SS + s] = (mask[b * SS + s] == 1) ? expf(scores[b * SS + s] - m) * inv : 0.f;
}

// Weighted accumulation: grid = B x (S/8) (4096: 16 WG/CU). Thread t owns
// cols 4t..4t+3 (float4 loads: 16B/lane, wave covers 1KB/instruction; the
// old version used 4B scalar loads). All TCH rows loaded to registers before
// the FMA chain. wtok chunk pre-staged in LDS; fast path when chunk crosses
// no boundary.
#define TCH 8
__global__ __launch_bounds__(256) void block_embed8_kernel(
    const float* __restrict__ hidden, const float* __restrict__ wtok,
    const int* __restrict__ bnd, float* __restrict__ embed)
{
    const int b = blockIdx.x >> 9;          // 512 chunks per batch
    const int ch = blockIdx.x & 511;
    const int t = threadIdx.x;
    __shared__ int bsh[KK];
    __shared__ float wsh[TCH];
    const int s0 = ch * TCH, s1 = s0 + TCH;
    if (t < KK) bsh[t] = bnd[b * KK + t];
    if (t >= 64 && t < 64 + TCH) wsh[t - 64] = wtok[b * SS + s0 + (t - 64)];
    __syncthreads();

    int cur = -1;
#pragma unroll
    for (int i = 0; i < KK; i++) cur = (bsh[i] <= s0) ? i : cur;
    const int nxt = (cur + 1 < KK) ? bsh[cur + 1] : INT_MAX;   // uniform

    const float* hr0 = hidden + ((long)b * SS + s0) * HH + 4 * t;

    if (nxt >= s1 && cur >= 0) {
        // fast path: whole chunk in one block; all loads in flight first
        float4 v[TCH];
#pragma unroll
        for (int i = 0; i < TCH; i++) v[i] = *(const float4*)(hr0 + (long)i * HH);
        float4 a = {0.f, 0.f, 0.f, 0.f};
#pragma unroll
        for (int i = 0; i < TCH; i++) {
            const float w = wsh[i];
            a.x = fmaf(w, v[i].x, a.x);
            a.y = fmaf(w, v[i].y, a.y);
            a.z = fmaf(w, v[i].z, a.z);
            a.w = fmaf(w, v[i].w, a.w);
        }
        float* e = embed + ((long)b * KK + cur) * HH + 4 * t;
        atomicAdd(e, a.x); atomicAdd(e + 1, a.y);
        atomicAdd(e + 2, a.z); atomicAdd(e + 3, a.w);
        return;
    }

    float4 a = {0.f, 0.f, 0.f, 0.f};
    bool any = false;
    for (int s = s0; s < s1; s++) {
        while (cur + 1 < KK && bsh[cur + 1] <= s) {
            if (any) {
                float* e = embed + ((long)b * KK + cur) * HH + 4 * t;
                atomicAdd(e, a.x); atomicAdd(e + 1, a.y);
                atomicAdd(e + 2, a.z); atomicAdd(e + 3, a.w);
                a = (float4){0.f, 0.f, 0.f, 0.f}; any = false;
            }
            cur++;
        }
        if (cur < 0) continue;
        const float w = wsh[s - s0];
        const float4 v = *(const float4*)(hr0 + (long)(s - s0) * HH);
        a.x = fmaf(w, v.x, a.x);
        a.y = fmaf(w, v.y, a.y);
        a.z = fmaf(w, v.z, a.z);
        a.w = fmaf(w, v.w, a.w);
        any = true;
    }
    if (any) {
        float* e = embed + ((long)b * KK + cur) * HH + 4 * t;
        atomicAdd(e, a.x); atomicAdd(e + 1, a.y);
        atomicAdd(e + 2, a.z); atomicAdd(e + 3, a.w);
    }
}

// Fused finalize A+B (grid B*8): block softmax -> func slice (128 h) in LDS ->
// partial GEMV -> osum[(b*8+hc)*EE + e] (non-atomic partials).
__global__ __launch_bounds__(256) void finalize_ab_kernel(
    const float* __restrict__ embed, const float* __restrict__ bscores,
    const float* __restrict__ bden, const float* __restrict__ out_w,
    float* __restrict__ osum)
{
    const int b = blockIdx.x >> 3, hc = blockIdx.x & 7;
    const int t = threadIdx.x;
    __shared__ float bw[KK];
    __shared__ float fpart[2][128];
    __shared__ float fsh[128];

    if (t < KK) {   // wave 0
        float s = (bden[b * KK + t] > 0.f) ? bscores[b * KK + t] : NEGF;
        float m = s;
        for (int off = 32; off > 0; off >>= 1) m = fmaxf(m, __shfl_xor(m, off, 64));
        float e = expf(s - m);
        float d = e;
        for (int off = 32; off > 0; off >>= 1) d += __shfl_xor(d, off, 64);
        bw[t] = e / d;
    }
    __syncthreads();

    {   // func slice: h = hc*128 + (t&127), k-half = t>>7
        const int hh = t & 127, kh = t >> 7;
        const float* ep = embed + ((long)b * KK + kh * 32) * HH + hc * 128 + hh;
        float f = 0.f;
#pragma unroll 8
        for (int k2 = 0; k2 < 32; k2++)
            f = fmaf(bw[kh * 32 + k2], ep[(long)k2 * HH], f);
        fpart[kh][hh] = f;
    }
    __syncthreads();
    if (t < 128) fsh[t] = fpart[0][t] + fpart[1][t];
    __syncthreads();

    float acc = 0.f;
    const float* wpp = out_w + (long)(hc * 128) * EE + t;
#pragma unroll 8
    for (int h = 0; h < 128; h++)
        acc = fmaf(fsh[h], wpp[(long)h * EE], acc);
    osum[(long)(b * 8 + hc) * EE + t] = acc;
}

// finalize C (grid B): reduce 8 partials + bias + L2 normalize
__global__ __launch_bounds__(256) void finalize_c_kernel(
    const float* __restrict__ osum, const float* __restrict__ out_b,
    float* __restrict__ outp)
{
    const int b = blockIdx.x, t = threadIdx.x;
    __shared__ float r4[4];
    float o = out_b[t];
#pragma unroll
    for (int hc = 0; hc < 8; hc++)
        o += osum[(long)(b * 8 + hc) * EE + t];
    float sq = o * o;
    for (int off = 32; off > 0; off >>= 1) sq += __shfl_down(sq, off, 64);
    if ((t & 63) == 0) r4[t >> 6] = sq;
    __syncthreads();
    const float nrm = sqrtf(r4[0] + r4[1] + r4[2] + r4[3]);
    outp[b * EE + t] = o / fmaxf(nrm, 1e-12f);
}

extern "C" void kernel_launch(void* const* d_in, const int* in_sizes, int n_in,
                              void* d_out, int out_size, void* d_ws, size_t ws_size,
                              hipStream_t stream) {
    const float* hidden  = (const float*)d_in[0];
    const int*   mask    = (const int*)  d_in[1];
    const int*   bnd     = (const int*)  d_in[2];
    const float* tok_w1  = (const float*)d_in[3];
    const float* tok_b1  = (const float*)d_in[4];
    const float* tok_w2  = (const float*)d_in[5];
    const float* tok_b2  = (const float*)d_in[6];
    const float* blk_w1  = (const float*)d_in[7];
    const float* blk_b1  = (const float*)d_in[8];
    const float* blk_w2  = (const float*)d_in[9];
    const float* blk_b2  = (const float*)d_in[10];
    const float* out_w   = (const float*)d_in[11];
    const float* out_b   = (const float*)d_in[12];

    float* ws      = (float*)d_ws;
    float* wtok    = ws;                       // [32768]
    float* embed   = ws + 32768;               // [524288]
    float* scores  = ws + 557056;              // [32768]
    float* bden    = ws + 589824;              // [512]
    float* bscores = ws + 590336;              // [512]
    float* osum    = ws + 590848;              // [16384]
    short* w1s_tok = (short*)(ws + 607232);    // [262144] bf16
    short* w1s_blk = w1s_tok + 262144;         // [262144] bf16

    convert_both_kernel<<<64, 256, 0, stream>>>(tok_w1, blk_w1, w1s_tok, w1s_blk);
    mfma_score32L_kernel<<<BB * SS / 32, 256, 0, stream>>>(
        hidden, w1s_tok, tok_b1, tok_w2, tok_b2, scores);
    block_stats_kernel<<<BB * KK, 256, 0, stream>>>(
        scores, mask, bnd, bden, wtok, embed);
    block_embed8_kernel<<<BB * SS / TCH, 256, 0, stream>>>(hidden, wtok, bnd, embed);
    mfma_score32L_kernel<<<BB * KK / 32, 256, 0, stream>>>(
        embed, w1s_blk, blk_b1, blk_w2, blk_b2, bscores);
    finalize_ab_kernel<<<BB * 8, 256, 0, stream>>>(
        embed, bscores, bden, out_w, osum);
    finalize_c_kernel<<<BB, 256, 0, stream>>>(osum, out_b, (float*)d_out);
}

// Round 7
// 289.883 us; speedup vs baseline: 1.2410x; 1.2410x over previous
//
#include <hip/hip_runtime.h>
#include <math.h>
#include <limits.h>

#define BB 8
#define SS 4096
#define HH 1024
#define EE 256
#define KK 64
#define HQ 256
#define NEGF -1e30f

typedef short bf16x8 __attribute__((ext_vector_type(8)));
typedef float f32x4  __attribute__((ext_vector_type(4)));

__device__ inline short f2bf(float x) {
    unsigned u = __float_as_uint(x);
    unsigned r = (u + 0x7fffu + ((u >> 16) & 1u)) >> 16;   // RNE
    return (short)r;
}

// pack two f32 into two bf16 (round-half-up)
__device__ inline unsigned pk2bf(float lo, float hi) {
    unsigned a = __float_as_uint(lo) + 0x8000u;
    unsigned b = __float_as_uint(hi) + 0x8000u;
    return (a >> 16) | (b & 0xffff0000u);
}

// Both weight conversions in one kernel. dst[kb][n][kk] = bf16(src[(kb*32+kk)*HQ+n])
__global__ __launch_bounds__(256) void convert_both_kernel(
    const float* __restrict__ tok_w1, const float* __restrict__ blk_w1,
    short* __restrict__ w1s_tok, short* __restrict__ w1s_blk)
{
    const int kb = blockIdx.x & 31, which = blockIdx.x >> 5;
    const float* src = which ? blk_w1 : tok_w1;
    short* dst = which ? w1s_blk : w1s_tok;
    const int n = threadIdx.x;
    for (int kk = 0; kk < 32; kk++)
        dst[kb * 8192 + n * 32 + kk] = f2bf(src[(kb * 32 + kk) * HQ + n]);
}

// Row scores: 32 rows/WG x 256 cols -> grid = M/32 (1024 for tokens: 4 WG/CU).
// Coalesced WG-cooperative A staging (fragment-ordered LDS, zero conflicts),
// CHUNKED: 4 k-steps per LDS buffer, double-buffered -> 1 barrier per 4 ksteps.
// Raw s_barrier + explicit lgkmcnt(0) drain (NO vmcnt drain). [r2 config:
// best measured of 5 structural variants, 76.8us]
__global__ __launch_bounds__(256, 4) void mfma_score4_kernel(
    const float* __restrict__ X, const short* __restrict__ w1s,
    const float* __restrict__ b1, const float* __restrict__ w2,
    const float* __restrict__ b2, float* __restrict__ out)
{
    __shared__ __attribute__((aligned(16))) short As[2][4][1024];  // 16 KB
    __shared__ float part[4][32];

    const int t = threadIdx.x;
    const int wv = t >> 6, lane = t & 63, lo = lane & 15, q = lane >> 4;
    const long row0 = (long)blockIdx.x * 32;

    f32x4 acc[2][4];
#pragma unroll
    for (int i = 0; i < 2; i++)
#pragma unroll
        for (int j = 0; j < 4; j++) acc[i][j] = (f32x4){0.f, 0.f, 0.f, 0.f};

    // staging: chunk-thread c = t>>1, half = t&1
    const int c = t >> 1, half = t & 1;
    const int srow = ((c >> 6) << 4) + (c & 15);
    const int skofs = ((c >> 4) & 3) * 8 + half * 4;
    const float* xs = X + (row0 + srow) * HH + skofs;
    const int dofs = c * 8 + half * 4;           // offset within one kstep's [1024]
    // B: wave wv, frag ct: lane(q,lo) -> n = wv*64+ct*16+lo, k = kb*32+q*8
    const short* wp = w1s + (wv * 64 + lo) * 32 + q * 8;

    float4 sv[4];
    bf16x8 bC[4], bN[4];

    // ---- prologue: chunk0 -> As[0]; issue chunk1 loads; B(kb=0) -> bC ----
#pragma unroll
    for (int j = 0; j < 4; j++) sv[j] = *(const float4*)(xs + j * 32);
#pragma unroll
    for (int j = 0; j < 4; j++) {
        unsigned u0 = pk2bf(sv[j].x, sv[j].y), u1 = pk2bf(sv[j].z, sv[j].w);
        unsigned* d = (unsigned*)&As[0][j][dofs];
        d[0] = u0; d[1] = u1;
    }
#pragma unroll
    for (int j = 0; j < 4; j++) sv[j] = *(const float4*)(xs + (4 + j) * 32);
#pragma unroll
    for (int ct = 0; ct < 4; ct++) bC[ct] = *(const bf16x8*)(wp + ct * 512);
    asm volatile("s_waitcnt lgkmcnt(0)" ::: "memory");
    __builtin_amdgcn_sched_barrier(0);
    __builtin_amdgcn_s_barrier();
    __builtin_amdgcn_sched_barrier(0);

#define KSTEP(J, BUSE, BPRE, KBN)                                              \
    {                                                                          \
        _Pragma("unroll")                                                      \
        for (int ct = 0; ct < 4; ct++)                                         \
            BPRE[ct] = *(const bf16x8*)(wp + (KBN) * 8192 + ct * 512);         \
        bf16x8 af0 = *(const bf16x8*)&As[cur][J][(q * 16 + lo) * 8];           \
        bf16x8 af1 = *(const bf16x8*)&As[cur][J][(64 + q * 16 + lo) * 8];      \
        _Pragma("unroll")                                                      \
        for (int ct = 0; ct < 4; ct++) {                                       \
            acc[0][ct] = __builtin_amdgcn_mfma_f32_16x16x32_bf16(              \
                af0, BUSE[ct], acc[0][ct], 0, 0, 0);                           \
            acc[1][ct] = __builtin_amdgcn_mfma_f32_16x16x32_bf16(              \
                af1, BUSE[ct], acc[1][ct], 0, 0, 0);                           \
        }                                                                      \
    }

    for (int ci = 0; ci < 8; ci++) {
        const int cur = ci & 1;
        const int kb0 = ci * 4;
        KSTEP(0, bC, bN, kb0 + 1)
        KSTEP(1, bN, bC, kb0 + 2)
        KSTEP(2, bC, bN, kb0 + 3)
        const int kbn3 = (kb0 + 4 < 32) ? kb0 + 4 : 31;   // dummy on last iter
        KSTEP(3, bN, bC, kbn3)
        if (ci < 7) {
            // write chunk ci+1 (loaded last body) into the other buffer
#pragma unroll
            for (int j = 0; j < 4; j++) {
                unsigned u0 = pk2bf(sv[j].x, sv[j].y), u1 = pk2bf(sv[j].z, sv[j].w);
                unsigned* d = (unsigned*)&As[cur ^ 1][j][dofs];
                d[0] = u0; d[1] = u1;
            }
            // issue loads for chunk ci+2 (clamped dummy near the end)
            const int cn = (ci + 2 < 8) ? ci + 2 : 7;
#pragma unroll
            for (int j = 0; j < 4; j++)
                sv[j] = *(const float4*)(xs + (cn * 4 + j) * 32);
        }
        asm volatile("s_waitcnt lgkmcnt(0)" ::: "memory");
        __builtin_amdgcn_sched_barrier(0);
        __builtin_amdgcn_s_barrier();
        __builtin_amdgcn_sched_barrier(0);
    }
#undef KSTEP

    // epilogue: rowpart[rt][r] = sum_c tanh(acc + b1[c]) * w2[c]
    float rowpart[2][4];
#pragma unroll
    for (int rt = 0; rt < 2; rt++)
#pragma unroll
        for (int r = 0; r < 4; r++) rowpart[rt][r] = 0.f;
#pragma unroll
    for (int ct = 0; ct < 4; ct++) {
        const int cc = wv * 64 + ct * 16 + lo;
        const float b1c = b1[cc], w2c = w2[cc];
#pragma unroll
        for (int rt = 0; rt < 2; rt++)
#pragma unroll
            for (int r = 0; r < 4; r++)
                rowpart[rt][r] += tanhf(acc[rt][ct][r] + b1c) * w2c;
    }
#pragma unroll
    for (int rt = 0; rt < 2; rt++)
#pragma unroll
        for (int r = 0; r < 4; r++) {
            float v = rowpart[rt][r];
            v += __shfl_down(v, 8, 64);
            v += __shfl_down(v, 4, 64);
            v += __shfl_down(v, 2, 64);
            v += __shfl_down(v, 1, 64);
            rowpart[rt][r] = v;   // valid where lo==0
        }
    if (lo == 0)
#pragma unroll
        for (int rt = 0; rt < 2; rt++)
#pragma unroll
            for (int r = 0; r < 4; r++)
                part[wv][rt * 16 + q * 4 + r] = rowpart[rt][r];
    __syncthreads();
    if (t < 32)
        out[row0 + t] = part[0][t] + part[1][t] + part[2][t] + part[3][t] + b2[0];
}

// Per (b,k): masked max + denom; write normalized wtok; zero embed row;
// k==0 also zeroes wtok[0, start).
__global__ __launch_bounds__(256) void block_stats_kernel(
    const float* __restrict__ scores, const int* __restrict__ mask,
    const int* __restrict__ bnd, float* __restrict__ bden,
    float* __restrict__ wtok, float* __restrict__ embed)
{
    const int b = blockIdx.x >> 6, k = blockIdx.x & 63;
    const int start = bnd[b * KK + k];
    const int end = (k == KK - 1) ? SS : bnd[b * KK + k + 1];
    const int tid = threadIdx.x;
    __shared__ float r[4];
    __shared__ float mshared, dshared;

    // zero this block's embed row (embed kernel runs after us)
    *((float4*)(embed + (long)blockIdx.x * HH) + tid) = (float4){0.f, 0.f, 0.f, 0.f};
    // zero the uncovered wtok prefix
    if (k == 0)
        for (int s = tid; s < start; s += 256) wtok[b * SS + s] = 0.f;

    float m = NEGF;
    for (int s = start + tid; s < end; s += 256)
        if (mask[b * SS + s] == 1) m = fmaxf(m, scores[b * SS + s]);
    for (int off = 32; off > 0; off >>= 1) m = fmaxf(m, __shfl_down(m, off, 64));
    if ((tid & 63) == 0) r[tid >> 6] = m;
    __syncthreads();
    if (tid == 0) mshared = fmaxf(fmaxf(r[0], r[1]), fmaxf(r[2], r[3]));
    __syncthreads();
    m = mshared;

    float d = 0.f;
    for (int s = start + tid; s < end; s += 256)
        if (mask[b * SS + s] == 1) d += expf(scores[b * SS + s] - m);
    for (int off = 32; off > 0; off >>= 1) d += __shfl_down(d, off, 64);
    __syncthreads();
    if ((tid & 63) == 0) r[tid >> 6] = d;
    __syncthreads();
    if (tid == 0) {
        float den = r[0] + r[1] + r[2] + r[3];
        bden[blockIdx.x] = den;
        dshared = (den > 0.f) ? 1.f / fmaxf(den, 1e-30f) : 0.f;
    }
    __syncthreads();
    const float inv = dshared;
    for (int s = start + tid; s < end; s += 256)
        wtok[b * SS + s] = (mask[b * SS + s] == 1) ? expf(scores[b * SS + s] - m) * inv : 0.f;
}

// Weighted accumulation: grid = B x (S/16) (2048: 8 WG/CU); thread t owns
// h = t, t+256, t+512, t+768 (lane-coalesced loads AND atomics). wtok chunk
// pre-staged in LDS; fast path when chunk crosses no boundary. [r2 config]
#define TCH 16
__global__ __launch_bounds__(256) void block_embed4_kernel(
    const float* __restrict__ hidden, const float* __restrict__ wtok,
    const int* __restrict__ bnd, float* __restrict__ embed)
{
    const int b = blockIdx.x >> 8;          // 256 chunks per batch
    const int ch = blockIdx.x & 255;
    const int t = threadIdx.x;
    __shared__ int bsh[KK];
    __shared__ float wsh[TCH];
    const int s0 = ch * TCH, s1 = s0 + TCH;
    if (t < KK) bsh[t] = bnd[b * KK + t];
    if (t >= 64 && t < 64 + TCH) wsh[t - 64] = wtok[b * SS + s0 + (t - 64)];
    __syncthreads();

    int cur = -1;
#pragma unroll
    for (int i = 0; i < KK; i++) cur = (bsh[i] <= s0) ? i : cur;
    const int nxt = (cur + 1 < KK) ? bsh[cur + 1] : INT_MAX;   // uniform

    const float* hr0 = hidden + ((long)b * SS + s0) * HH + t;
    float a0 = 0.f, a1 = 0.f, a2 = 0.f, a3 = 0.f;

    if (nxt >= s1 && cur >= 0) {
        // fast path: whole chunk in one block, branch-free
#pragma unroll
        for (int i = 0; i < TCH; i++) {
            const float w = wsh[i];
            const float* hr = hr0 + (long)i * HH;
            a0 = fmaf(w, hr[0], a0);
            a1 = fmaf(w, hr[256], a1);
            a2 = fmaf(w, hr[512], a2);
            a3 = fmaf(w, hr[768], a3);
        }
        float* e = embed + ((long)b * KK + cur) * HH;
        atomicAdd(e + t, a0); atomicAdd(e + t + 256, a1);
        atomicAdd(e + t + 512, a2); atomicAdd(e + t + 768, a3);
        return;
    }

    bool any = false;
    for (int s = s0; s < s1; s++) {
        while (cur + 1 < KK && bsh[cur + 1] <= s) {
            if (any) {
                float* e = embed + ((long)b * KK + cur) * HH;
                atomicAdd(e + t, a0); atomicAdd(e + t + 256, a1);
                atomicAdd(e + t + 512, a2); atomicAdd(e + t + 768, a3);
                a0 = a1 = a2 = a3 = 0.f; any = false;
            }
            cur++;
        }
        if (cur < 0) continue;
        const float w = wsh[s - s0];
        const float* hr = hr0 + (long)(s - s0) * HH;
        a0 = fmaf(w, hr[0], a0);
        a1 = fmaf(w, hr[256], a1);
        a2 = fmaf(w, hr[512], a2);
        a3 = fmaf(w, hr[768], a3);
        any = true;
    }
    if (any) {
        float* e = embed + ((long)b * KK + cur) * HH;
        atomicAdd(e + t, a0); atomicAdd(e + t + 256, a1);
        atomicAdd(e + t + 512, a2); atomicAdd(e + t + 768, a3);
    }
}

// Fused finalize A+B, 4x h-split (grid B*8*4 = 256 WGs -> 1 WG/CU, was 64):
// WG (b,hc,hq) owns 32 h-rows [hc*128+hq*32 .. +32): block softmax -> func
// slice (32 h) in LDS -> partial GEMV over its h-rows -> osum[(b*32+hc*4+hq)].
// Also cuts out_w reads 64MB->8MB and embed reads 16MB->2MB vs the 64-WG ver.
__global__ __launch_bounds__(256) void finalize_ab_kernel(
    const float* __restrict__ embed, const float* __restrict__ bscores,
    const float* __restrict__ bden, const float* __restrict__ out_w,
    float* __restrict__ osum)
{
    const int b = blockIdx.x >> 5;
    const int hc = (blockIdx.x >> 2) & 7;
    const int hq = blockIdx.x & 3;
    const int t = threadIdx.x;
    __shared__ float bw[KK];
    __shared__ float fpart[8][32];
    __shared__ float fsh[32];

    if (t < KK) {   // wave 0
        float s = (bden[b * KK + t] > 0.f) ? bscores[b * KK + t] : NEGF;
        float m = s;
        for (int off = 32; off > 0; off >>= 1) m = fmaxf(m, __shfl_xor(m, off, 64));
        float e = expf(s - m);
        float d = e;
        for (int off = 32; off > 0; off >>= 1) d += __shfl_xor(d, off, 64);
        bw[t] = e / d;
    }
    __syncthreads();

    const int hbase = hc * 128 + hq * 32;
    {   // func slice for 32 h's: hh = t&31, k-group kh = t>>5 (8 groups x 8 k)
        const int hh = t & 31, kh = t >> 5;
        const float* ep = embed + ((long)b * KK + kh * 8) * HH + hbase + hh;
        float f = 0.f;
#pragma unroll
        for (int k2 = 0; k2 < 8; k2++)
            f = fmaf(bw[kh * 8 + k2], ep[(long)k2 * HH], f);
        fpart[kh][hh] = f;
    }
    __syncthreads();
    if (t < 32) {
        float f = 0.f;
#pragma unroll
        for (int g = 0; g < 8; g++) f += fpart[g][t];
        fsh[t] = f;
    }
    __syncthreads();

    float acc = 0.f;
    const float* wpp = out_w + (long)hbase * EE + t;
#pragma unroll
    for (int h = 0; h < 32; h++)
        acc = fmaf(fsh[h], wpp[(long)h * EE], acc);
    osum[(long)(b * 32 + hc * 4 + hq) * EE + t] = acc;
}

// finalize C (grid B): reduce 32 partials + bias + L2 normalize
__global__ __launch_bounds__(256) void finalize_c_kernel(
    const float* __restrict__ osum, const float* __restrict__ out_b,
    float* __restrict__ outp)
{
    const int b = blockIdx.x, t = threadIdx.x;
    __shared__ float r4[4];
    float o = out_b[t];
#pragma unroll
    for (int hc = 0; hc < 32; hc++)
        o += osum[(long)(b * 32 + hc) * EE + t];
    float sq = o * o;
    for (int off = 32; off > 0; off >>= 1) sq += __shfl_down(sq, off, 64);
    if ((t & 63) == 0) r4[t >> 6] = sq;
    __syncthreads();
    const float nrm = sqrtf(r4[0] + r4[1] + r4[2] + r4[3]);
    outp[b * EE + t] = o / fmaxf(nrm, 1e-12f);
}

extern "C" void kernel_launch(void* const* d_in, const int* in_sizes, int n_in,
                              void* d_out, int out_size, void* d_ws, size_t ws_size,
                              hipStream_t stream) {
    const float* hidden  = (const float*)d_in[0];
    const int*   mask    = (const int*)  d_in[1];
    const int*   bnd     = (const int*)  d_in[2];
    const float* tok_w1  = (const float*)d_in[3];
    const float* tok_b1  = (const float*)d_in[4];
    const float* tok_w2  = (const float*)d_in[5];
    const float* tok_b2  = (const float*)d_in[6];
    const float* blk_w1  = (const float*)d_in[7];
    const float* blk_b1  = (const float*)d_in[8];
    const float* blk_w2  = (const float*)d_in[9];
    const float* blk_b2  = (const float*)d_in[10];
    const float* out_w   = (const float*)d_in[11];
    const float* out_b   = (const float*)d_in[12];

    float* ws      = (float*)d_ws;
    float* wtok    = ws;                       // [32768]
    float* embed   = ws + 32768;               // [524288]
    float* scores  = ws + 557056;              // [32768]
    float* bden    = ws + 589824;              // [512]
    float* bscores = ws + 590336;              // [512]
    float* osum    = ws + 590848;              // [65536]
    short* w1s_tok = (short*)(ws + 656384);    // [262144] bf16
    short* w1s_blk = w1s_tok + 262144;         // [262144] bf16

    convert_both_kernel<<<64, 256, 0, stream>>>(tok_w1, blk_w1, w1s_tok, w1s_blk);
    mfma_score4_kernel<<<BB * SS / 32, 256, 0, stream>>>(
        hidden, w1s_tok, tok_b1, tok_w2, tok_b2, scores);
    block_stats_kernel<<<BB * KK, 256, 0, stream>>>(
        scores, mask, bnd, bden, wtok, embed);
    block_embed4_kernel<<<BB * SS / TCH, 256, 0, stream>>>(hidden, wtok, bnd, embed);
    mfma_score4_kernel<<<BB * KK / 32, 256, 0, stream>>>(
        embed, w1s_blk, blk_b1, blk_w2, blk_b2, bscores);
    finalize_ab_kernel<<<BB * 32, 256, 0, stream>>>(
        embed, bscores, bden, out_w, osum);
    finalize_c_kernel<<<BB, 256, 0, stream>>>(osum, out_b, (float*)d_out);
}